// Round 11
// baseline (50.543 us; speedup 1.0000x reference)
//
#include <hip/hip_runtime.h>

// Problem constants (fixed by the reference)
constexpr int B = 8, T = 128, S = 256, H = 512;

typedef __attribute__((ext_vector_type(4))) float f32x4;
typedef __attribute__((ext_vector_type(8))) float f32x8;
typedef __attribute__((ext_vector_type(8))) short short8;
typedef __attribute__((ext_vector_type(4))) short short4v;

#define DEVINL __device__ __forceinline__

DEVINL float bf2f(short s) {
  union { unsigned u; float f; } x;
  x.u = ((unsigned)(unsigned short)s) << 16;
  return x.f;
}
// fp32 -> bf16 round-to-nearest-even (finite inputs)
DEVINL short f2bf(float f) {
  unsigned u = __float_as_uint(f);
  return (short)((u + 0x7fffu + ((u >> 16) & 1u)) >> 16);
}
DEVINL float fast_tanh(float x) {
  float e = __builtin_amdgcn_exp2f(x * 2.8853900817779268f);
  return 1.0f - 2.0f * __builtin_amdgcn_rcpf(e + 1.0f);
}

constexpr float C2 = 2.8853900817779268f;   // 2*log2(e) — folded into W_s, W_h at prep
constexpr float L2E = 1.4426950408889634f;  // log2(e)

// ---- workspace layout (units: shorts) — ~11.5 MiB ----
constexpr size_t OFF_EH  = 0;                               // exp2(hs') PACKED [b][h/8][s][8] bf16 (B*H*S)
constexpr size_t OFF_PT  = OFF_EH + (size_t)B * H * S;      // P^T = (enc@W1^T)^T bf16 [b][n][s] (B*H*S)
constexpr size_t OFF_ATT = OFF_PT + (size_t)B * H * S;      // attn bf16    (B*T*S)
constexpr size_t OFF_QBF = OFF_ATT + (size_t)B * T * S;     // query bf16   (B*T*H)
constexpr size_t OFF_EBF = OFF_QBF + (size_t)B * T * H;     // enc bf16     (B*S*H)
constexpr size_t OFF_WSB = OFF_EBF + (size_t)B * S * H;     // C2*W_s bf16  (H*H)
constexpr size_t OFF_WHB = OFF_WSB + (size_t)H * H;         // C2*W_h bf16  (H*H)
constexpr size_t OFF_WOB = OFF_WHB + (size_t)H * H;         // W_out bf16   (H*2H)
constexpr size_t OFF_EQ  = OFF_WOB + (size_t)H * 2 * H;     // exp2(qs') f32 (B*T*H floats)

// ---- prep: one-time f32 -> bf16 of all GEMM operands (W_s,W_h pre-scaled by C2).
// vec4 counts: q 131072 | e 262144 | Ws 65536 | Wh 65536 | Wo 131072 ; cum 131072,393216,458752,524288,655360
__global__ __launch_bounds__(256) void prep_kernel(
    const float* __restrict__ q, const float* __restrict__ e,
    const float* __restrict__ ws, const float* __restrict__ wh,
    const float* __restrict__ wo, short* __restrict__ base) {
  int vi = blockIdx.x * 256 + threadIdx.x;
  if (vi >= 655360) return;
  const float* src; short* dst; int local; float scale;
  if (vi < 131072)      { src = q;  dst = base + OFF_QBF; local = vi;          scale = 1.f; }
  else if (vi < 393216) { src = e;  dst = base + OFF_EBF; local = vi - 131072; scale = 1.f; }
  else if (vi < 458752) { src = ws; dst = base + OFF_WSB; local = vi - 393216; scale = C2;  }
  else if (vi < 524288) { src = wh; dst = base + OFF_WHB; local = vi - 458752; scale = C2;  }
  else                  { src = wo; dst = base + OFF_WOB; local = vi - 524288; scale = 1.f; }
  float4 f = reinterpret_cast<const float4*>(src)[local];
  short4v o;
  o.x = f2bf(f.x * scale); o.y = f2bf(f.y * scale);
  o.z = f2bf(f.z * scale); o.w = f2bf(f.w * scale);
  *reinterpret_cast<short4v*>(dst + (size_t)local * 4) = o;
}

// ---- MFMA GEMM core, all-bf16 staging. Tile (MB*32) x (NB*32), 256 thr =
// 4 waves (2x2); wave owns (MB*16)x(NB*16); BK=64, XOR-swizzled LDS.
// C[m][n] = sum_k A[m][k] * Wt[n][k]; acc flattened [MB][NB]. ----
template <int MB, int NB>
DEVINL void gemm_tile_bf(const short* __restrict__ A, int lda,
                         const short* __restrict__ Wt, int ldw, int K,
                         int bm, int bn, short* As, short* Bs, f32x4* acc) {
  const int tid = threadIdx.x;
  const int lane = tid & 63;
  const int wm = (tid >> 6) >> 1, wn = (tid >> 6) & 1;
  const int g = lane >> 4, r = lane & 15;
  for (int k0 = 0; k0 < K; k0 += 64) {
    __syncthreads();
#pragma unroll
    for (int p = 0; p < MB; ++p) {     // stage A: MB*32 rows x 8 chunks
      const int idx = p * 256 + tid;
      const int row = idx >> 3, c = idx & 7;
      short8 av = *reinterpret_cast<const short8*>(&A[(size_t)(bm + row) * lda + k0 + c * 8]);
      *reinterpret_cast<short8*>(&As[row * 64 + ((c ^ (row & 7)) * 8)]) = av;
    }
#pragma unroll
    for (int p = 0; p < NB; ++p) {     // stage B: NB*32 rows x 8 chunks
      const int idx = p * 256 + tid;
      const int row = idx >> 3, c = idx & 7;
      short8 wv = *reinterpret_cast<const short8*>(&Wt[(size_t)(bn + row) * ldw + k0 + c * 8]);
      *reinterpret_cast<short8*>(&Bs[row * 64 + ((c ^ (row & 7)) * 8)]) = wv;
    }
    __syncthreads();
#pragma unroll
    for (int kc = 0; kc < 2; ++kc) {
      short8 af[MB], bfr[NB];
#pragma unroll
      for (int mb = 0; mb < MB; ++mb) {
        const int ra = wm * (MB * 16) + mb * 16 + r;
        af[mb] = *reinterpret_cast<const short8*>(&As[ra * 64 + (((kc * 4 + g) ^ (r & 7)) * 8)]);
      }
#pragma unroll
      for (int nb = 0; nb < NB; ++nb) {
        const int rb = wn * (NB * 16) + nb * 16 + r;
        bfr[nb] = *reinterpret_cast<const short8*>(&Bs[rb * 64 + (((kc * 4 + g) ^ (r & 7)) * 8)]);
      }
#pragma unroll
      for (int mb = 0; mb < MB; ++mb)
#pragma unroll
        for (int nb = 0; nb < NB; ++nb)
          acc[mb * NB + nb] =
              __builtin_amdgcn_mfma_f32_16x16x32_bf16(af[mb], bfr[nb], acc[mb * NB + nb], 0, 0, 0);
    }
  }
}

// K2: 64x128 tiles (N covered by 4 tiles of 128).
//   blocks [0,64):    eq  = exp2(q_bf @ (C2*W_s)^T) -> f32 [b*T+t][h]
//   blocks [64,192):  eh  = exp2(e_bf @ (C2*W_h)^T) -> bf16 PACKED [b][h/8][s][h%8]
//   blocks [192,320): P^T = (e_bf @ Wo[:,:H]^T)^T   -> bf16 [b][n][s]
__global__ __launch_bounds__(256) void proj_kernel(short* __restrict__ wsbase,
                                                   float* __restrict__ eq) {
  __shared__ short As[64 * 64], Bs[128 * 64];
  f32x4 acc[8];
#pragma unroll
  for (int i = 0; i < 8; ++i) acc[i] = (f32x4){0.f, 0.f, 0.f, 0.f};
  int bid = blockIdx.x;
  int mode; const short* A; const short* W; int ldw;
  const short* q_bf = wsbase + OFF_QBF;
  const short* e_bf = wsbase + OFF_EBF;
  if (bid < 64)       { mode = 0; A = q_bf; W = wsbase + OFF_WSB; ldw = H; }
  else if (bid < 192) { mode = 1; bid -= 64; A = e_bf; W = wsbase + OFF_WHB; ldw = H; }
  else                { mode = 2; bid -= 192; A = e_bf; W = wsbase + OFF_WOB; ldw = 2 * H; }
  const int bm = (bid >> 2) * 64, bn = (bid & 3) * 128;
  gemm_tile_bf<2, 4>(A, H, W, ldw, H, bm, bn, As, Bs, acc);

  short* eh_p = wsbase + OFF_EH;
  short* P_t = wsbase + OFF_PT;
  const int lane = threadIdx.x & 63, wave = threadIdx.x >> 6;
  const int wm = wave >> 1, wn = wave & 1, g = lane >> 4, r = lane & 15;
#pragma unroll
  for (int mb = 0; mb < 2; ++mb)
#pragma unroll
    for (int nb = 0; nb < 4; ++nb) {
      const f32x4 a4 = acc[mb * 4 + nb];
      const int m0 = bm + wm * 32 + mb * 16 + g * 4;  // base of 4 consecutive rows
      const int col = bn + wn * 64 + nb * 16 + r;
      if (mode == 0) {
#pragma unroll
        for (int i = 0; i < 4; ++i)
          eq[(size_t)(m0 + i) * H + col] = __builtin_amdgcn_exp2f(a4[i]);
      } else if (mode == 1) {
        // rows are s-consecutive within one b (64-row tile stays inside one b)
        const int bb = m0 >> 8, sl = m0 & 255;
        const size_t base = ((size_t)(bb * (H / 8) + (col >> 3)) * S + sl) * 8 + (col & 7);
#pragma unroll
        for (int i = 0; i < 4; ++i)
          eh_p[base + (size_t)i * 8] = f2bf(__builtin_amdgcn_exp2f(a4[i]));
      } else {
        const int bb = m0 >> 8, sl = m0 & 255;
        short4v o;
        o.x = f2bf(a4[0]); o.y = f2bf(a4[1]); o.z = f2bf(a4[2]); o.w = f2bf(a4[3]);
        *reinterpret_cast<short4v*>(&P_t[((size_t)bb * H + col) * S + sl]) = o;
      }
    }
}

// K3: scores + softmax -> attn bf16.
// Block = 2 t-rows: 512 thr = 8 waves = 4 s-groups x 2 H-halves; lane owns s=sg*64+lane.
// tanh(q+h) = 1 - 2*rcp(fma(eq,eh,1)); Sum_h v_h dropped (softmax shift-invariance).
// Pairwise rcp: va*rcp(A)+vb*rcp(B) = (va*B+vb*A)*rcp(A*B) — halves quarter-rate trans.
// Superchunk = 16 h; ALL streams (eh, q, v) prefetched one superchunk ahead.
__global__ __launch_bounds__(512) void attn_kernel(
    const float* __restrict__ eq, const short* __restrict__ eh_p,
    const float* __restrict__ v, const int* __restrict__ lens,
    short* __restrict__ attn_bf) {
  __shared__ float s_part[2][2][S];            // [half][tt][s]
  __shared__ float red_m[2][4], red_s[2][4];   // [tt][sg]
  const int tid = threadIdx.x, lane = tid & 63;
  const int wu = __builtin_amdgcn_readfirstlane(tid >> 6);  // uniform wave id
  const int sg = wu & 3, half = wu >> 2;
  const int b = blockIdx.x >> 6;               // 64 blocks per batch (T/2)
  const int t0 = (blockIdx.x & 63) * 2;
  const int s = sg * 64 + lane;

  const float* qp0 = eq + (size_t)(b * T + t0) * H + half * (H / 2);  // uniform
  const float* qp1 = qp0 + H;                                          // uniform
  const float* vp = v + half * (H / 2);                                // uniform
  const short8* ep = reinterpret_cast<const short8*>(eh_p) +
                     ((size_t)(b * (H / 8) + half * (H / 16)) * S + s);

  float acc0 = 0.f, acc1 = 0.f;
  short8 e0 = ep[0], e1 = ep[(size_t)S];
  f32x8 qA0 = *reinterpret_cast<const f32x8*>(qp0);
  f32x8 qB0 = *reinterpret_cast<const f32x8*>(qp0 + 8);
  f32x8 qA1 = *reinterpret_cast<const f32x8*>(qp1);
  f32x8 qB1 = *reinterpret_cast<const f32x8*>(qp1 + 8);
  f32x8 vA = *reinterpret_cast<const f32x8*>(vp);
  f32x8 vB = *reinterpret_cast<const f32x8*>(vp + 8);
  for (int it = 0; it < 16; ++it) {
    // prefetch next superchunk (last iter reloads chunk 0; values unused)
    const int nh = (it < 15) ? (it + 1) * 16 : 0;
    const size_t ne = (it < 15) ? (size_t)(2 * it + 2) * S : 0;
    const short8 e0n = ep[ne], e1n = ep[ne + S];
    const f32x8 qA0n = *reinterpret_cast<const f32x8*>(qp0 + nh);
    const f32x8 qB0n = *reinterpret_cast<const f32x8*>(qp0 + nh + 8);
    const f32x8 qA1n = *reinterpret_cast<const f32x8*>(qp1 + nh);
    const f32x8 qB1n = *reinterpret_cast<const f32x8*>(qp1 + nh + 8);
    const f32x8 vAn = *reinterpret_cast<const f32x8*>(vp + nh);
    const f32x8 vBn = *reinterpret_cast<const f32x8*>(vp + nh + 8);
#pragma unroll
    for (int j = 0; j < 8; j += 2) {
      const float ea = bf2f(e0[j]), eb = bf2f(e0[j + 1]);
      {  // t0
        const float Aa = fmaf(qA0[j], ea, 1.0f);
        const float Bb = fmaf(qA0[j + 1], eb, 1.0f);
        const float rr = __builtin_amdgcn_rcpf(Aa * Bb);
        const float num = fmaf(vA[j + 1], Aa, vA[j] * Bb);
        acc0 = fmaf(num, rr, acc0);
      }
      {  // t1
        const float Aa = fmaf(qA1[j], ea, 1.0f);
        const float Bb = fmaf(qA1[j + 1], eb, 1.0f);
        const float rr = __builtin_amdgcn_rcpf(Aa * Bb);
        const float num = fmaf(vA[j + 1], Aa, vA[j] * Bb);
        acc1 = fmaf(num, rr, acc1);
      }
    }
#pragma unroll
    for (int j = 0; j < 8; j += 2) {
      const float ea = bf2f(e1[j]), eb = bf2f(e1[j + 1]);
      {  // t0
        const float Aa = fmaf(qB0[j], ea, 1.0f);
        const float Bb = fmaf(qB0[j + 1], eb, 1.0f);
        const float rr = __builtin_amdgcn_rcpf(Aa * Bb);
        const float num = fmaf(vB[j + 1], Aa, vB[j] * Bb);
        acc0 = fmaf(num, rr, acc0);
      }
      {  // t1
        const float Aa = fmaf(qB1[j], ea, 1.0f);
        const float Bb = fmaf(qB1[j + 1], eb, 1.0f);
        const float rr = __builtin_amdgcn_rcpf(Aa * Bb);
        const float num = fmaf(vB[j + 1], Aa, vB[j] * Bb);
        acc1 = fmaf(num, rr, acc1);
      }
    }
    e0 = e0n; e1 = e1n;
    qA0 = qA0n; qB0 = qB0n; qA1 = qA1n; qB1 = qB1n;
    vA = vAn; vB = vBn;
  }
  s_part[half][0][s] = acc0;
  s_part[half][1][s] = acc1;
  __syncthreads();

  // all 8 waves redundantly finalize (uniform control flow; identical values)
  const int len = lens[b];
  const float a0 = s_part[0][0][s] + s_part[1][0][s];
  const float a1 = s_part[0][1][s] + s_part[1][1][s];
  const float y0 = (s < len) ? (-2.0f * L2E * a0) : -1e30f;  // log2-domain scores
  const float y1 = (s < len) ? (-2.0f * L2E * a1) : -1e30f;
  float m0 = y0, m1 = y1;
#pragma unroll
  for (int off = 32; off > 0; off >>= 1) {
    m0 = fmaxf(m0, __shfl_xor(m0, off));
    m1 = fmaxf(m1, __shfl_xor(m1, off));
  }
  if (lane == 0) { red_m[0][sg] = m0; red_m[1][sg] = m1; }
  __syncthreads();
  const float mt0 = fmaxf(fmaxf(red_m[0][0], red_m[0][1]), fmaxf(red_m[0][2], red_m[0][3]));
  const float mt1 = fmaxf(fmaxf(red_m[1][0], red_m[1][1]), fmaxf(red_m[1][2], red_m[1][3]));
  const float p0 = __builtin_amdgcn_exp2f(y0 - mt0);
  const float p1 = __builtin_amdgcn_exp2f(y1 - mt1);
  float u0 = p0, u1 = p1;
#pragma unroll
  for (int off = 32; off > 0; off >>= 1) {
    u0 += __shfl_xor(u0, off);
    u1 += __shfl_xor(u1, off);
  }
  if (lane == 0) { red_s[0][sg] = u0; red_s[1][sg] = u1; }
  __syncthreads();
  if (half == 0) {
    const float tot0 = red_s[0][0] + red_s[0][1] + red_s[0][2] + red_s[0][3];
    const float tot1 = red_s[1][0] + red_s[1][1] + red_s[1][2] + red_s[1][3];
    attn_bf[(size_t)(b * T + t0) * S + s] = f2bf(p0 * __builtin_amdgcn_rcpf(tot0));
    attn_bf[(size_t)(b * T + t0 + 1) * S + s] = f2bf(p1 * __builtin_amdgcn_rcpf(tot1));
  }
}

// K4: out = tanh(attn @ P^T + q_bf @ W2^T + b_out), f32 out. 32x128 tiles, 128 blocks.
__global__ __launch_bounds__(256) void out_kernel(
    const short* __restrict__ wsbase, const float* __restrict__ bias,
    float* __restrict__ out) {
  __shared__ short As[32 * 64], Bs[128 * 64];
  f32x4 acc[4];
#pragma unroll
  for (int i = 0; i < 4; ++i) acc[i] = (f32x4){0.f, 0.f, 0.f, 0.f};
  const int bm = (blockIdx.x >> 2) * 32, bn = (blockIdx.x & 3) * 128;
  const int batch = bm >> 7;               // T = 128 rows per batch
  const short* attn_bf = wsbase + OFF_ATT;
  const short* P_t = wsbase + OFF_PT;
  const short* q_bf = wsbase + OFF_QBF;
  const short* Wob = wsbase + OFF_WOB;
  gemm_tile_bf<1, 4>(attn_bf, S, P_t + (size_t)batch * H * S, S, S, bm, bn, As, Bs, acc);
  gemm_tile_bf<1, 4>(q_bf, H, Wob + H, 2 * H, H, bm, bn, As, Bs, acc);
  const int lane = threadIdx.x & 63, wave = threadIdx.x >> 6;
  const int wm = wave >> 1, wn = wave & 1, g = lane >> 4, r = lane & 15;
#pragma unroll
  for (int nb = 0; nb < 4; ++nb) {
    const f32x4 a4 = acc[nb];
    const int col = bn + wn * 64 + nb * 16 + r;
    const float bb = bias[col];
#pragma unroll
    for (int i = 0; i < 4; ++i) {
      const int row = bm + wm * 16 + g * 4 + i;
      out[(size_t)row * H + col] = fast_tanh(a4[i] + bb);
    }
  }
}

extern "C" void kernel_launch(void* const* d_in, const int* in_sizes, int n_in,
                              void* d_out, int out_size, void* d_ws, size_t ws_size,
                              hipStream_t stream) {
  const float* query = (const float*)d_in[0];  // (B,T,H)
  const float* enc = (const float*)d_in[1];    // (B,S,H)
  const int* lens = (const int*)d_in[2];       // (B)
  const float* W_s = (const float*)d_in[3];    // (H,H)
  const float* W_h = (const float*)d_in[4];    // (H,H)
  const float* v = (const float*)d_in[5];      // (H)
  const float* W_out = (const float*)d_in[6];  // (H,2H)
  const float* b_out = (const float*)d_in[7];  // (H)
  float* out = (float*)d_out;                  // (B,T,H)

  short* wsb = (short*)d_ws;
  short* eh_p = wsb + OFF_EH;
  short* attn_bf = wsb + OFF_ATT;
  float* eq = (float*)(wsb + OFF_EQ);

  prep_kernel<<<2560, 256, 0, stream>>>(query, enc, W_s, W_h, W_out, wsb);
  proj_kernel<<<320, 256, 0, stream>>>(wsb, eq);
  attn_kernel<<<B * T / 2, 512, 0, stream>>>(eq, eh_p, v, lens, attn_bf);
  out_kernel<<<128, 256, 0, stream>>>(wsb, b_out, out);
}

// Round 12
// 47.820 us; speedup vs baseline: 1.0570x; 1.0570x over previous
//
#include <hip/hip_runtime.h>

// Problem constants (fixed by the reference)
constexpr int B = 8, T = 128, S = 256, H = 512;

typedef __attribute__((ext_vector_type(4))) float f32x4;
typedef __attribute__((ext_vector_type(8))) float f32x8;
typedef __attribute__((ext_vector_type(8))) short short8;
typedef __attribute__((ext_vector_type(4))) short short4v;

#define DEVINL __device__ __forceinline__

DEVINL float bf2f(short s) {
  union { unsigned u; float f; } x;
  x.u = ((unsigned)(unsigned short)s) << 16;
  return x.f;
}
// fp32 -> bf16 round-to-nearest-even (finite inputs)
DEVINL short f2bf(float f) {
  unsigned u = __float_as_uint(f);
  return (short)((u + 0x7fffu + ((u >> 16) & 1u)) >> 16);
}
DEVINL float fast_tanh(float x) {
  float e = __builtin_amdgcn_exp2f(x * 2.8853900817779268f);
  return 1.0f - 2.0f * __builtin_amdgcn_rcpf(e + 1.0f);
}

constexpr float C2 = 2.8853900817779268f;   // 2*log2(e) — folded into W_s, W_h at prep
constexpr float L2E = 1.4426950408889634f;  // log2(e)

// ---- workspace layout (units: shorts) — ~11.5 MiB ----
constexpr size_t OFF_EH  = 0;                               // exp2(hs') PACKED [b][h/8][s][8] bf16 (B*H*S)
constexpr size_t OFF_PT  = OFF_EH + (size_t)B * H * S;      // P^T = (enc@W1^T)^T bf16 [b][n][s] (B*H*S)
constexpr size_t OFF_ATT = OFF_PT + (size_t)B * H * S;      // attn bf16    (B*T*S)
constexpr size_t OFF_QBF = OFF_ATT + (size_t)B * T * S;     // query bf16   (B*T*H)
constexpr size_t OFF_EBF = OFF_QBF + (size_t)B * T * H;     // enc bf16     (B*S*H)
constexpr size_t OFF_WSB = OFF_EBF + (size_t)B * S * H;     // C2*W_s bf16  (H*H)
constexpr size_t OFF_WHB = OFF_WSB + (size_t)H * H;         // C2*W_h bf16  (H*H)
constexpr size_t OFF_WOB = OFF_WHB + (size_t)H * H;         // W_out bf16   (H*2H)
constexpr size_t OFF_EQ  = OFF_WOB + (size_t)H * 2 * H;     // exp2(qs') f32 (B*T*H floats)

// ---- prep: one-time f32 -> bf16 of all GEMM operands (W_s,W_h pre-scaled by C2).
__global__ __launch_bounds__(256) void prep_kernel(
    const float* __restrict__ q, const float* __restrict__ e,
    const float* __restrict__ ws, const float* __restrict__ wh,
    const float* __restrict__ wo, short* __restrict__ base) {
  int vi = blockIdx.x * 256 + threadIdx.x;
  if (vi >= 655360) return;
  const float* src; short* dst; int local; float scale;
  if (vi < 131072)      { src = q;  dst = base + OFF_QBF; local = vi;          scale = 1.f; }
  else if (vi < 393216) { src = e;  dst = base + OFF_EBF; local = vi - 131072; scale = 1.f; }
  else if (vi < 458752) { src = ws; dst = base + OFF_WSB; local = vi - 393216; scale = C2;  }
  else if (vi < 524288) { src = wh; dst = base + OFF_WHB; local = vi - 458752; scale = C2;  }
  else                  { src = wo; dst = base + OFF_WOB; local = vi - 524288; scale = 1.f; }
  float4 f = reinterpret_cast<const float4*>(src)[local];
  short4v o;
  o.x = f2bf(f.x * scale); o.y = f2bf(f.y * scale);
  o.z = f2bf(f.z * scale); o.w = f2bf(f.w * scale);
  *reinterpret_cast<short4v*>(dst + (size_t)local * 4) = o;
}

// ---- MFMA GEMM core, all-bf16 staging. Tile (MB*32) x (NB*32), 256 thr =
// 4 waves (2x2); BK=64, XOR-swizzled LDS. C[m][n] = sum_k A[m][k]*Wt[n][k]. ----
template <int MB, int NB>
DEVINL void gemm_tile_bf(const short* __restrict__ A, int lda,
                         const short* __restrict__ Wt, int ldw, int K,
                         int bm, int bn, short* As, short* Bs, f32x4* acc) {
  const int tid = threadIdx.x;
  const int lane = tid & 63;
  const int wm = (tid >> 6) >> 1, wn = (tid >> 6) & 1;
  const int g = lane >> 4, r = lane & 15;
  for (int k0 = 0; k0 < K; k0 += 64) {
    __syncthreads();
#pragma unroll
    for (int p = 0; p < MB; ++p) {     // stage A: MB*32 rows x 8 chunks
      const int idx = p * 256 + tid;
      const int row = idx >> 3, c = idx & 7;
      short8 av = *reinterpret_cast<const short8*>(&A[(size_t)(bm + row) * lda + k0 + c * 8]);
      *reinterpret_cast<short8*>(&As[row * 64 + ((c ^ (row & 7)) * 8)]) = av;
    }
#pragma unroll
    for (int p = 0; p < NB; ++p) {     // stage B: NB*32 rows x 8 chunks
      const int idx = p * 256 + tid;
      const int row = idx >> 3, c = idx & 7;
      short8 wv = *reinterpret_cast<const short8*>(&Wt[(size_t)(bn + row) * ldw + k0 + c * 8]);
      *reinterpret_cast<short8*>(&Bs[row * 64 + ((c ^ (row & 7)) * 8)]) = wv;
    }
    __syncthreads();
#pragma unroll
    for (int kc = 0; kc < 2; ++kc) {
      short8 af[MB], bfr[NB];
#pragma unroll
      for (int mb = 0; mb < MB; ++mb) {
        const int ra = wm * (MB * 16) + mb * 16 + r;
        af[mb] = *reinterpret_cast<const short8*>(&As[ra * 64 + (((kc * 4 + g) ^ (r & 7)) * 8)]);
      }
#pragma unroll
      for (int nb = 0; nb < NB; ++nb) {
        const int rb = wn * (NB * 16) + nb * 16 + r;
        bfr[nb] = *reinterpret_cast<const short8*>(&Bs[rb * 64 + (((kc * 4 + g) ^ (r & 7)) * 8)]);
      }
#pragma unroll
      for (int mb = 0; mb < MB; ++mb)
#pragma unroll
        for (int nb = 0; nb < NB; ++nb)
          acc[mb * NB + nb] =
              __builtin_amdgcn_mfma_f32_16x16x32_bf16(af[mb], bfr[nb], acc[mb * NB + nb], 0, 0, 0);
    }
  }
}

// K2: 64x64 tiles, 640 blocks (r10-proven balance).
//   blocks [0,128):   eq  = exp2(q_bf @ (C2*W_s)^T) -> f32 [b*T+t][h]
//   blocks [128,384): eh  = exp2(e_bf @ (C2*W_h)^T) -> bf16 PACKED [b][h/8][s][h%8]
//   blocks [384,640): P^T = (e_bf @ Wo[:,:H]^T)^T   -> bf16 [b][n][s]
__global__ __launch_bounds__(256) void proj_kernel(short* __restrict__ wsbase,
                                                   float* __restrict__ eq) {
  __shared__ short As[64 * 64], Bs[64 * 64];
  f32x4 acc[4];
#pragma unroll
  for (int i = 0; i < 4; ++i) acc[i] = (f32x4){0.f, 0.f, 0.f, 0.f};
  int bid = blockIdx.x;
  int mode; const short* A; const short* W; int ldw;
  const short* q_bf = wsbase + OFF_QBF;
  const short* e_bf = wsbase + OFF_EBF;
  if (bid < 128)      { mode = 0; A = q_bf; W = wsbase + OFF_WSB; ldw = H; }
  else if (bid < 384) { mode = 1; bid -= 128; A = e_bf; W = wsbase + OFF_WHB; ldw = H; }
  else                { mode = 2; bid -= 384; A = e_bf; W = wsbase + OFF_WOB; ldw = 2 * H; }
  const int bm = (bid >> 3) * 64, bn = (bid & 7) * 64;
  gemm_tile_bf<2, 2>(A, H, W, ldw, H, bm, bn, As, Bs, acc);

  short* eh_p = wsbase + OFF_EH;
  short* P_t = wsbase + OFF_PT;
  const int lane = threadIdx.x & 63, wave = threadIdx.x >> 6;
  const int wm = wave >> 1, wn = wave & 1, g = lane >> 4, r = lane & 15;
#pragma unroll
  for (int mb = 0; mb < 2; ++mb)
#pragma unroll
    for (int nb = 0; nb < 2; ++nb) {
      const f32x4 a4 = acc[mb * 2 + nb];
      const int m0 = bm + wm * 32 + mb * 16 + g * 4;  // base of 4 consecutive rows
      const int col = bn + wn * 32 + nb * 16 + r;
      if (mode == 0) {
#pragma unroll
        for (int i = 0; i < 4; ++i)
          eq[(size_t)(m0 + i) * H + col] = __builtin_amdgcn_exp2f(a4[i]);
      } else if (mode == 1) {
        // rows are s-consecutive within one b (64-row tile stays inside one b)
        const int bb = m0 >> 8, sl = m0 & 255;
        const size_t base = ((size_t)(bb * (H / 8) + (col >> 3)) * S + sl) * 8 + (col & 7);
#pragma unroll
        for (int i = 0; i < 4; ++i)
          eh_p[base + (size_t)i * 8] = f2bf(__builtin_amdgcn_exp2f(a4[i]));
      } else {
        const int bb = m0 >> 8, sl = m0 & 255;
        short4v o;
        o.x = f2bf(a4[0]); o.y = f2bf(a4[1]); o.z = f2bf(a4[2]); o.w = f2bf(a4[3]);
        *reinterpret_cast<short4v*>(&P_t[((size_t)bb * H + col) * S + sl]) = o;
      }
    }
}

// K3: scores + softmax -> attn bf16.
// Block = 4 t-rows: 1024 thr = 16 waves = 4 s-groups x 4 H-quarters; lane owns
// s = sg*64+lane and ALL 4 t-rows (eh load + bf16 cvt shared across t).
// tanh(q+h) = 1 - 2*rcp(fma(eq,eh,1)); Sum_h v_h dropped (softmax shift-invariance).
// Pairwise rcp: va*rcp(A)+vb*rcp(B) = (va*B+vb*A)*rcp(A*B). eh prefetch depth 2.
// q/v pointers wave-uniform -> scalar loads. Grid = 256 blocks (1 per CU).
__global__ __launch_bounds__(1024) void attn_kernel(
    const float* __restrict__ eq, const short* __restrict__ eh_p,
    const float* __restrict__ v, const int* __restrict__ lens,
    short* __restrict__ attn_bf) {
  __shared__ float s_part[4][4][S];            // [quarter][tt][s] = 16 KB
  __shared__ float red_m[4][4], red_s[4][4];   // [tt][sg]
  const int tid = threadIdx.x, lane = tid & 63;
  const int wu = __builtin_amdgcn_readfirstlane(tid >> 6);  // uniform wave id 0..15
  const int sg = wu & 3, qtr = wu >> 2;
  const int b = blockIdx.x >> 5;               // 32 blocks per batch (T/4)
  const int t0 = (blockIdx.x & 31) * 4;
  const int s = sg * 64 + lane;

  const float* qp = eq + (size_t)(b * T + t0) * H + qtr * (H / 4);  // uniform
  const float* vp = v + qtr * (H / 4);                               // uniform
  const short8* ep = reinterpret_cast<const short8*>(eh_p) +
                     ((size_t)(b * (H / 8) + qtr * (H / 32)) * S + s);

  float acc[4] = {0.f, 0.f, 0.f, 0.f};
  short8 e0 = ep[0], e1 = ep[(size_t)S];
  for (int it = 0; it < 8; ++it) {   // 8 superchunks of 16 h over this quarter
    const size_t ne = (it < 7) ? (size_t)(2 * it + 2) * S : 0;
    const short8 e0n = ep[ne], e1n = ep[ne + S];
    const int h = it * 16;
    float ef[16];
#pragma unroll
    for (int j = 0; j < 8; ++j) { ef[j] = bf2f(e0[j]); ef[8 + j] = bf2f(e1[j]); }
    const f32x8 vA = *reinterpret_cast<const f32x8*>(vp + h);
    const f32x8 vB = *reinterpret_cast<const f32x8*>(vp + h + 8);
#pragma unroll
    for (int tt = 0; tt < 4; ++tt) {
      const float* qq = qp + (size_t)tt * H + h;
      const f32x8 qA = *reinterpret_cast<const f32x8*>(qq);      // scalar loads
      const f32x8 qB = *reinterpret_cast<const f32x8*>(qq + 8);
#pragma unroll
      for (int j = 0; j < 8; j += 2) {
        const float Aa = fmaf(qA[j], ef[j], 1.0f);
        const float Bb = fmaf(qA[j + 1], ef[j + 1], 1.0f);
        const float rr = __builtin_amdgcn_rcpf(Aa * Bb);
        acc[tt] = fmaf(fmaf(vA[j + 1], Aa, vA[j] * Bb), rr, acc[tt]);
      }
#pragma unroll
      for (int j = 0; j < 8; j += 2) {
        const float Aa = fmaf(qB[j], ef[8 + j], 1.0f);
        const float Bb = fmaf(qB[j + 1], ef[8 + j + 1], 1.0f);
        const float rr = __builtin_amdgcn_rcpf(Aa * Bb);
        acc[tt] = fmaf(fmaf(vB[j + 1], Aa, vB[j] * Bb), rr, acc[tt]);
      }
    }
    e0 = e0n; e1 = e1n;
  }
#pragma unroll
  for (int tt = 0; tt < 4; ++tt) s_part[qtr][tt][s] = acc[tt];
  __syncthreads();

  // all waves redundantly combine quarters (uniform control flow)
  const int len = lens[b];
  float y[4], m[4];
#pragma unroll
  for (int tt = 0; tt < 4; ++tt) {
    const float a = s_part[0][tt][s] + s_part[1][tt][s] + s_part[2][tt][s] + s_part[3][tt][s];
    y[tt] = (s < len) ? (-2.0f * L2E * a) : -1e30f;  // log2-domain score
    m[tt] = y[tt];
#pragma unroll
    for (int off = 32; off > 0; off >>= 1) m[tt] = fmaxf(m[tt], __shfl_xor(m[tt], off));
  }
  if (qtr == 0 && lane == 0) {
#pragma unroll
    for (int tt = 0; tt < 4; ++tt) red_m[tt][sg] = m[tt];
  }
  __syncthreads();
  float p[4], u[4];
#pragma unroll
  for (int tt = 0; tt < 4; ++tt) {
    const float mt = fmaxf(fmaxf(red_m[tt][0], red_m[tt][1]),
                           fmaxf(red_m[tt][2], red_m[tt][3]));
    p[tt] = __builtin_amdgcn_exp2f(y[tt] - mt);
    u[tt] = p[tt];
#pragma unroll
    for (int off = 32; off > 0; off >>= 1) u[tt] += __shfl_xor(u[tt], off);
  }
  if (qtr == 0 && lane == 0) {
#pragma unroll
    for (int tt = 0; tt < 4; ++tt) red_s[tt][sg] = u[tt];
  }
  __syncthreads();
  if (qtr == 0) {
#pragma unroll
    for (int tt = 0; tt < 4; ++tt) {
      const float tot = red_s[tt][0] + red_s[tt][1] + red_s[tt][2] + red_s[tt][3];
      attn_bf[(size_t)(b * T + t0 + tt) * S + s] = f2bf(p[tt] * __builtin_amdgcn_rcpf(tot));
    }
  }
}

// K4: out = tanh(attn @ P^T + q_bf @ W2^T + b_out), f32 out. 32x64 tiles, 256 blocks.
__global__ __launch_bounds__(256) void out_kernel(
    const short* __restrict__ wsbase, const float* __restrict__ bias,
    float* __restrict__ out) {
  __shared__ short As[32 * 64], Bs[64 * 64];
  f32x4 acc[2];
#pragma unroll
  for (int i = 0; i < 2; ++i) acc[i] = (f32x4){0.f, 0.f, 0.f, 0.f};
  const int bm = (blockIdx.x >> 3) * 32, bn = (blockIdx.x & 7) * 64;
  const int batch = bm >> 7;               // T = 128 rows per batch
  const short* attn_bf = wsbase + OFF_ATT;
  const short* P_t = wsbase + OFF_PT;
  const short* q_bf = wsbase + OFF_QBF;
  const short* Wob = wsbase + OFF_WOB;
  gemm_tile_bf<1, 2>(attn_bf, S, P_t + (size_t)batch * H * S, S, S, bm, bn, As, Bs, acc);
  gemm_tile_bf<1, 2>(q_bf, H, Wob + H, 2 * H, H, bm, bn, As, Bs, acc);
  const int lane = threadIdx.x & 63, wave = threadIdx.x >> 6;
  const int wm = wave >> 1, wn = wave & 1, g = lane >> 4, r = lane & 15;
#pragma unroll
  for (int nb = 0; nb < 2; ++nb) {
    const f32x4 a4 = acc[nb];
    const int col = bn + wn * 32 + nb * 16 + r;
    const float bb = bias[col];
#pragma unroll
    for (int i = 0; i < 4; ++i) {
      const int row = bm + wm * 16 + g * 4 + i;
      out[(size_t)row * H + col] = fast_tanh(a4[i] + bb);
    }
  }
}

extern "C" void kernel_launch(void* const* d_in, const int* in_sizes, int n_in,
                              void* d_out, int out_size, void* d_ws, size_t ws_size,
                              hipStream_t stream) {
  const float* query = (const float*)d_in[0];  // (B,T,H)
  const float* enc = (const float*)d_in[1];    // (B,S,H)
  const int* lens = (const int*)d_in[2];       // (B)
  const float* W_s = (const float*)d_in[3];    // (H,H)
  const float* W_h = (const float*)d_in[4];    // (H,H)
  const float* v = (const float*)d_in[5];      // (H)
  const float* W_out = (const float*)d_in[6];  // (H,2H)
  const float* b_out = (const float*)d_in[7];  // (H)
  float* out = (float*)d_out;                  // (B,T,H)

  short* wsb = (short*)d_ws;
  short* eh_p = wsb + OFF_EH;
  short* attn_bf = wsb + OFF_ATT;
  float* eq = (float*)(wsb + OFF_EQ);

  prep_kernel<<<2560, 256, 0, stream>>>(query, enc, W_s, W_h, W_out, wsb);
  proj_kernel<<<640, 256, 0, stream>>>(wsb, eq);
  attn_kernel<<<B * T / 4, 1024, 0, stream>>>(eq, eh_p, v, lens, attn_bf);
  out_kernel<<<256, 256, 0, stream>>>(wsb, b_out, out);
}

// Round 13
// 44.840 us; speedup vs baseline: 1.1272x; 1.0664x over previous
//
#include <hip/hip_runtime.h>

// Problem constants (fixed by the reference)
constexpr int B = 8, T = 128, S = 256, H = 512;

typedef __attribute__((ext_vector_type(4))) float f32x4;
typedef __attribute__((ext_vector_type(8))) float f32x8;
typedef __attribute__((ext_vector_type(8))) short short8;
typedef __attribute__((ext_vector_type(4))) short short4v;

#define DEVINL __device__ __forceinline__

DEVINL float bf2f(short s) {
  union { unsigned u; float f; } x;
  x.u = ((unsigned)(unsigned short)s) << 16;
  return x.f;
}
// fp32 -> bf16 round-to-nearest-even (finite inputs)
DEVINL short f2bf(float f) {
  unsigned u = __float_as_uint(f);
  return (short)((u + 0x7fffu + ((u >> 16) & 1u)) >> 16);
}
DEVINL float fast_tanh(float x) {
  float e = __builtin_amdgcn_exp2f(x * 2.8853900817779268f);
  return 1.0f - 2.0f * __builtin_amdgcn_rcpf(e + 1.0f);
}

constexpr float C2 = 2.8853900817779268f;   // 2*log2(e) — folded into W_s, W_h at prep
constexpr float L2E = 1.4426950408889634f;  // log2(e)

// ---- workspace layout (units: shorts) — ~11.5 MiB ----
constexpr size_t OFF_EH  = 0;                               // exp2(hs') PACKED [b][h/8][s][8] bf16 (B*H*S)
constexpr size_t OFF_PT  = OFF_EH + (size_t)B * H * S;      // P^T = (enc@W1^T)^T bf16 [b][n][s] (B*H*S)
constexpr size_t OFF_ATT = OFF_PT + (size_t)B * H * S;      // attn bf16    (B*T*S)
constexpr size_t OFF_QBF = OFF_ATT + (size_t)B * T * S;     // query bf16   (B*T*H)
constexpr size_t OFF_EBF = OFF_QBF + (size_t)B * T * H;     // enc bf16     (B*S*H)
constexpr size_t OFF_WSB = OFF_EBF + (size_t)B * S * H;     // C2*W_s bf16  (H*H)
constexpr size_t OFF_WHB = OFF_WSB + (size_t)H * H;         // C2*W_h bf16  (H*H)
constexpr size_t OFF_WOB = OFF_WHB + (size_t)H * H;         // W_out bf16   (H*2H)
constexpr size_t OFF_EQ  = OFF_WOB + (size_t)H * 2 * H;     // exp2(qs') f32 (B*T*H floats)

// ---- prep: one-time f32 -> bf16 of all GEMM operands (W_s,W_h pre-scaled by C2).
__global__ __launch_bounds__(256) void prep_kernel(
    const float* __restrict__ q, const float* __restrict__ e,
    const float* __restrict__ ws, const float* __restrict__ wh,
    const float* __restrict__ wo, short* __restrict__ base) {
  int vi = blockIdx.x * 256 + threadIdx.x;
  if (vi >= 655360) return;
  const float* src; short* dst; int local; float scale;
  if (vi < 131072)      { src = q;  dst = base + OFF_QBF; local = vi;          scale = 1.f; }
  else if (vi < 393216) { src = e;  dst = base + OFF_EBF; local = vi - 131072; scale = 1.f; }
  else if (vi < 458752) { src = ws; dst = base + OFF_WSB; local = vi - 393216; scale = C2;  }
  else if (vi < 524288) { src = wh; dst = base + OFF_WHB; local = vi - 458752; scale = C2;  }
  else                  { src = wo; dst = base + OFF_WOB; local = vi - 524288; scale = 1.f; }
  float4 f = reinterpret_cast<const float4*>(src)[local];
  short4v o;
  o.x = f2bf(f.x * scale); o.y = f2bf(f.y * scale);
  o.z = f2bf(f.z * scale); o.w = f2bf(f.w * scale);
  *reinterpret_cast<short4v*>(dst + (size_t)local * 4) = o;
}

// ---- MFMA GEMM core, all-bf16 staging. Tile (MB*32) x (NB*32), 256 thr =
// 4 waves (2x2); BK=64, XOR-swizzled LDS. C[m][n] = sum_k A[m][k]*Wt[n][k]. ----
template <int MB, int NB>
DEVINL void gemm_tile_bf(const short* __restrict__ A, int lda,
                         const short* __restrict__ Wt, int ldw, int K,
                         int bm, int bn, short* As, short* Bs, f32x4* acc) {
  const int tid = threadIdx.x;
  const int lane = tid & 63;
  const int wm = (tid >> 6) >> 1, wn = (tid >> 6) & 1;
  const int g = lane >> 4, r = lane & 15;
  for (int k0 = 0; k0 < K; k0 += 64) {
    __syncthreads();
#pragma unroll
    for (int p = 0; p < MB; ++p) {     // stage A: MB*32 rows x 8 chunks
      const int idx = p * 256 + tid;
      const int row = idx >> 3, c = idx & 7;
      short8 av = *reinterpret_cast<const short8*>(&A[(size_t)(bm + row) * lda + k0 + c * 8]);
      *reinterpret_cast<short8*>(&As[row * 64 + ((c ^ (row & 7)) * 8)]) = av;
    }
#pragma unroll
    for (int p = 0; p < NB; ++p) {     // stage B: NB*32 rows x 8 chunks
      const int idx = p * 256 + tid;
      const int row = idx >> 3, c = idx & 7;
      short8 wv = *reinterpret_cast<const short8*>(&Wt[(size_t)(bn + row) * ldw + k0 + c * 8]);
      *reinterpret_cast<short8*>(&Bs[row * 64 + ((c ^ (row & 7)) * 8)]) = wv;
    }
    __syncthreads();
#pragma unroll
    for (int kc = 0; kc < 2; ++kc) {
      short8 af[MB], bfr[NB];
#pragma unroll
      for (int mb = 0; mb < MB; ++mb) {
        const int ra = wm * (MB * 16) + mb * 16 + r;
        af[mb] = *reinterpret_cast<const short8*>(&As[ra * 64 + (((kc * 4 + g) ^ (r & 7)) * 8)]);
      }
#pragma unroll
      for (int nb = 0; nb < NB; ++nb) {
        const int rb = wn * (NB * 16) + nb * 16 + r;
        bfr[nb] = *reinterpret_cast<const short8*>(&Bs[rb * 64 + (((kc * 4 + g) ^ (r & 7)) * 8)]);
      }
#pragma unroll
      for (int mb = 0; mb < MB; ++mb)
#pragma unroll
        for (int nb = 0; nb < NB; ++nb)
          acc[mb * NB + nb] =
              __builtin_amdgcn_mfma_f32_16x16x32_bf16(af[mb], bfr[nb], acc[mb * NB + nb], 0, 0, 0);
    }
  }
}

// K2: 64x64 tiles, 640 blocks.
//   blocks [0,128):   eq  = exp2(q_bf @ (C2*W_s)^T) -> f32 [b*T+t][h]
//   blocks [128,384): eh  = exp2(e_bf @ (C2*W_h)^T) -> bf16 PACKED [b][h/8][s][h%8]
//   blocks [384,640): P^T = (e_bf @ Wo[:,:H]^T)^T   -> bf16 [b][n][s]
__global__ __launch_bounds__(256) void proj_kernel(short* __restrict__ wsbase,
                                                   float* __restrict__ eq) {
  __shared__ short As[64 * 64], Bs[64 * 64];
  f32x4 acc[4];
#pragma unroll
  for (int i = 0; i < 4; ++i) acc[i] = (f32x4){0.f, 0.f, 0.f, 0.f};
  int bid = blockIdx.x;
  int mode; const short* A; const short* W; int ldw;
  const short* q_bf = wsbase + OFF_QBF;
  const short* e_bf = wsbase + OFF_EBF;
  if (bid < 128)      { mode = 0; A = q_bf; W = wsbase + OFF_WSB; ldw = H; }
  else if (bid < 384) { mode = 1; bid -= 128; A = e_bf; W = wsbase + OFF_WHB; ldw = H; }
  else                { mode = 2; bid -= 384; A = e_bf; W = wsbase + OFF_WOB; ldw = 2 * H; }
  const int bm = (bid >> 3) * 64, bn = (bid & 7) * 64;
  gemm_tile_bf<2, 2>(A, H, W, ldw, H, bm, bn, As, Bs, acc);

  short* eh_p = wsbase + OFF_EH;
  short* P_t = wsbase + OFF_PT;
  const int lane = threadIdx.x & 63, wave = threadIdx.x >> 6;
  const int wm = wave >> 1, wn = wave & 1, g = lane >> 4, r = lane & 15;
#pragma unroll
  for (int mb = 0; mb < 2; ++mb)
#pragma unroll
    for (int nb = 0; nb < 2; ++nb) {
      const f32x4 a4 = acc[mb * 2 + nb];
      const int m0 = bm + wm * 32 + mb * 16 + g * 4;  // base of 4 consecutive rows
      const int col = bn + wn * 32 + nb * 16 + r;
      if (mode == 0) {
#pragma unroll
        for (int i = 0; i < 4; ++i)
          eq[(size_t)(m0 + i) * H + col] = __builtin_amdgcn_exp2f(a4[i]);
      } else if (mode == 1) {
        // rows are s-consecutive within one b (64-row tile stays inside one b)
        const int bb = m0 >> 8, sl = m0 & 255;
        const size_t base = ((size_t)(bb * (H / 8) + (col >> 3)) * S + sl) * 8 + (col & 7);
#pragma unroll
        for (int i = 0; i < 4; ++i)
          eh_p[base + (size_t)i * 8] = f2bf(__builtin_amdgcn_exp2f(a4[i]));
      } else {
        const int bb = m0 >> 8, sl = m0 & 255;
        short4v o;
        o.x = f2bf(a4[0]); o.y = f2bf(a4[1]); o.z = f2bf(a4[2]); o.w = f2bf(a4[3]);
        *reinterpret_cast<short4v*>(&P_t[((size_t)bb * H + col) * S + sl]) = o;
      }
    }
}

// K3: scores + softmax -> attn bf16.
// Block = 2 t-rows: 1024 thr = 16 waves = 4 s-groups x 4 H-quarters; lane owns
// s = sg*64+lane and both t-rows. Grid 512 = 2 blocks/CU = 32 waves/CU = 8/SIMD
// (hardware max occupancy — this kernel is LATENCY-bound, per r6 counters).
// tanh(q+h) = 1 - 2*rcp(fma(eq,eh,1)); Sum_h v_h dropped (softmax shift-invariance).
// Pairwise rcp: va*rcp(A)+vb*rcp(B) = (va*B+vb*A)*rcp(A*B). eh prefetch depth 2.
// q/v pointers wave-uniform -> scalar (SGPR) loads; VGPR kept <= 64 for 8/SIMD.
__global__ __launch_bounds__(1024, 8) void attn_kernel(
    const float* __restrict__ eq, const short* __restrict__ eh_p,
    const float* __restrict__ v, const int* __restrict__ lens,
    short* __restrict__ attn_bf) {
  __shared__ float s_part[4][2][S];            // [quarter][tt][s] = 8 KB
  __shared__ float red_m[2][4], red_s[2][4];   // [tt][sg]
  const int tid = threadIdx.x, lane = tid & 63;
  const int wu = __builtin_amdgcn_readfirstlane(tid >> 6);  // uniform wave id 0..15
  const int sg = wu & 3, qtr = wu >> 2;
  const int b = blockIdx.x >> 6;               // 64 blocks per batch (T/2)
  const int t0 = (blockIdx.x & 63) * 2;
  const int s = sg * 64 + lane;

  const float* qp = eq + (size_t)(b * T + t0) * H + qtr * (H / 4);  // uniform
  const float* vp = v + qtr * (H / 4);                               // uniform
  const short8* ep = reinterpret_cast<const short8*>(eh_p) +
                     ((size_t)(b * (H / 8) + qtr * (H / 32)) * S + s);

  float acc0 = 0.f, acc1 = 0.f;
  short8 e0 = ep[0], e1 = ep[(size_t)S];
  for (int it = 0; it < 8; ++it) {   // 8 superchunks of 16 h over this quarter
    const size_t ne = (it < 7) ? (size_t)(2 * it + 2) * S : 0;
    const short8 e0n = ep[ne], e1n = ep[ne + S];
    const int h = it * 16;
    float ef[16];
#pragma unroll
    for (int j = 0; j < 8; ++j) { ef[j] = bf2f(e0[j]); ef[8 + j] = bf2f(e1[j]); }
    const f32x8 vA = *reinterpret_cast<const f32x8*>(vp + h);     // scalar loads
    const f32x8 vB = *reinterpret_cast<const f32x8*>(vp + h + 8);
#pragma unroll
    for (int tt = 0; tt < 2; ++tt) {
      const float* qq = qp + (size_t)tt * H + h;
      const f32x8 qA = *reinterpret_cast<const f32x8*>(qq);       // scalar loads
      const f32x8 qB = *reinterpret_cast<const f32x8*>(qq + 8);
      float a = 0.f;
#pragma unroll
      for (int j = 0; j < 8; j += 2) {
        const float Aa = fmaf(qA[j], ef[j], 1.0f);
        const float Bb = fmaf(qA[j + 1], ef[j + 1], 1.0f);
        const float rr = __builtin_amdgcn_rcpf(Aa * Bb);
        a = fmaf(fmaf(vA[j + 1], Aa, vA[j] * Bb), rr, a);
      }
#pragma unroll
      for (int j = 0; j < 8; j += 2) {
        const float Aa = fmaf(qB[j], ef[8 + j], 1.0f);
        const float Bb = fmaf(qB[j + 1], ef[8 + j + 1], 1.0f);
        const float rr = __builtin_amdgcn_rcpf(Aa * Bb);
        a = fmaf(fmaf(vB[j + 1], Aa, vB[j] * Bb), rr, a);
      }
      if (tt == 0) acc0 += a; else acc1 += a;
    }
    e0 = e0n; e1 = e1n;
  }
  s_part[qtr][0][s] = acc0;
  s_part[qtr][1][s] = acc1;
  __syncthreads();

  // all waves redundantly combine quarters (uniform control flow)
  const int len = lens[b];
  const float a0 = s_part[0][0][s] + s_part[1][0][s] + s_part[2][0][s] + s_part[3][0][s];
  const float a1 = s_part[0][1][s] + s_part[1][1][s] + s_part[2][1][s] + s_part[3][1][s];
  const float y0 = (s < len) ? (-2.0f * L2E * a0) : -1e30f;  // log2-domain scores
  const float y1 = (s < len) ? (-2.0f * L2E * a1) : -1e30f;
  float m0 = y0, m1 = y1;
#pragma unroll
  for (int off = 32; off > 0; off >>= 1) {
    m0 = fmaxf(m0, __shfl_xor(m0, off));
    m1 = fmaxf(m1, __shfl_xor(m1, off));
  }
  if (qtr == 0 && lane == 0) { red_m[0][sg] = m0; red_m[1][sg] = m1; }
  __syncthreads();
  const float mt0 = fmaxf(fmaxf(red_m[0][0], red_m[0][1]), fmaxf(red_m[0][2], red_m[0][3]));
  const float mt1 = fmaxf(fmaxf(red_m[1][0], red_m[1][1]), fmaxf(red_m[1][2], red_m[1][3]));
  const float p0 = __builtin_amdgcn_exp2f(y0 - mt0);
  const float p1 = __builtin_amdgcn_exp2f(y1 - mt1);
  float u0 = p0, u1 = p1;
#pragma unroll
  for (int off = 32; off > 0; off >>= 1) {
    u0 += __shfl_xor(u0, off);
    u1 += __shfl_xor(u1, off);
  }
  if (qtr == 0 && lane == 0) { red_s[0][sg] = u0; red_s[1][sg] = u1; }
  __syncthreads();
  if (qtr == 0) {
    const float tot0 = red_s[0][0] + red_s[0][1] + red_s[0][2] + red_s[0][3];
    const float tot1 = red_s[1][0] + red_s[1][1] + red_s[1][2] + red_s[1][3];
    attn_bf[(size_t)(b * T + t0) * S + s] = f2bf(p0 * __builtin_amdgcn_rcpf(tot0));
    attn_bf[(size_t)(b * T + t0 + 1) * S + s] = f2bf(p1 * __builtin_amdgcn_rcpf(tot1));
  }
}

// K4: out = tanh(attn @ P^T + q_bf @ W2^T + b_out), f32 out. 32x64 tiles, 256 blocks.
__global__ __launch_bounds__(256) void out_kernel(
    const short* __restrict__ wsbase, const float* __restrict__ bias,
    float* __restrict__ out) {
  __shared__ short As[32 * 64], Bs[64 * 64];
  f32x4 acc[2];
#pragma unroll
  for (int i = 0; i < 2; ++i) acc[i] = (f32x4){0.f, 0.f, 0.f, 0.f};
  const int bm = (blockIdx.x >> 3) * 32, bn = (blockIdx.x & 7) * 64;
  const int batch = bm >> 7;               // T = 128 rows per batch
  const short* attn_bf = wsbase + OFF_ATT;
  const short* P_t = wsbase + OFF_PT;
  const short* q_bf = wsbase + OFF_QBF;
  const short* Wob = wsbase + OFF_WOB;
  gemm_tile_bf<1, 2>(attn_bf, S, P_t + (size_t)batch * H * S, S, S, bm, bn, As, Bs, acc);
  gemm_tile_bf<1, 2>(q_bf, H, Wob + H, 2 * H, H, bm, bn, As, Bs, acc);
  const int lane = threadIdx.x & 63, wave = threadIdx.x >> 6;
  const int wm = wave >> 1, wn = wave & 1, g = lane >> 4, r = lane & 15;
#pragma unroll
  for (int nb = 0; nb < 2; ++nb) {
    const f32x4 a4 = acc[nb];
    const int col = bn + wn * 32 + nb * 16 + r;
    const float bb = bias[col];
#pragma unroll
    for (int i = 0; i < 4; ++i) {
      const int row = bm + wm * 16 + g * 4 + i;
      out[(size_t)row * H + col] = fast_tanh(a4[i] + bb);
    }
  }
}

extern "C" void kernel_launch(void* const* d_in, const int* in_sizes, int n_in,
                              void* d_out, int out_size, void* d_ws, size_t ws_size,
                              hipStream_t stream) {
  const float* query = (const float*)d_in[0];  // (B,T,H)
  const float* enc = (const float*)d_in[1];    // (B,S,H)
  const int* lens = (const int*)d_in[2];       // (B)
  const float* W_s = (const float*)d_in[3];    // (H,H)
  const float* W_h = (const float*)d_in[4];    // (H,H)
  const float* v = (const float*)d_in[5];      // (H)
  const float* W_out = (const float*)d_in[6];  // (H,2H)
  const float* b_out = (const float*)d_in[7];  // (H)
  float* out = (float*)d_out;                  // (B,T,H)

  short* wsb = (short*)d_ws;
  short* eh_p = wsb + OFF_EH;
  short* attn_bf = wsb + OFF_ATT;
  float* eq = (float*)(wsb + OFF_EQ);

  prep_kernel<<<2560, 256, 0, stream>>>(query, enc, W_s, W_h, W_out, wsb);
  proj_kernel<<<640, 256, 0, stream>>>(wsb, eq);
  attn_kernel<<<B * T / 2, 1024, 0, stream>>>(eq, eh_p, v, lens, attn_bf);
  out_kernel<<<256, 256, 0, stream>>>(wsb, b_out, out);
}